// Round 4
// baseline (76.965 us; speedup 1.0000x reference)
//
#include <hip/hip_runtime.h>
#include <math.h>

// Problem constants (B=1, H=16, S=2048, MAX_SEQ_LEN=2048 == S)
constexpr int S = 2048;
constexpr int HS = 16 * S;             // number of rows = H*S
constexpr long long OUTQ_ELEMS = (long long)HS * S;  // 67,108,864

// Native clang vector types — required by __builtin_nontemporal_load/store.
typedef int   vint4   __attribute__((ext_vector_type(4)));
typedef float vfloat4 __attribute__((ext_vector_type(4)));

// One WAVE (64 lanes) per row; 4 rows per 256-thread block.
// Row = 8 chunks of 256 elements; lane l covers chunk*256 + l*4 (int4).
// Chunk validity vs the causal bound i is WAVE-UNIFORM -> s_cbranch_execz
// skips loads+exps for fully-masked chunks; only the boundary chunk needs
// per-lane predication. Reduction is pure shfl_xor: no LDS, no barrier.
//
// Numerics: x = x_q*sx, x_q in [-64,63], sx in [0.005,0.02] => x in
// [-1.28,1.26]; exp(x) in [0.28,3.53], row sum <= 7230 — softmax without
// max-subtraction is exactly safe in fp32 (verified absmax 0.0 in round 3).
__global__ __launch_bounds__(256) void softmax_quant_wave_kernel(
    const int*   __restrict__ x_q,       // (H, S, S) int32
    const float* __restrict__ scale_x,   // (H, 2048)
    const float* __restrict__ scale_out, // (H, 2048)
    float*       __restrict__ out_q,     // (H, S, S) as float32
    float*       __restrict__ so_out)    // (H, S)    as float32
{
    const int tid  = threadIdx.x;
    const int lane = tid & 63;
    const int wave = tid >> 6;
    const int row  = blockIdx.x * 4 + wave;   // h*S + i
    const int i    = row & (S - 1);

    const float sx = scale_x[row];
    const float so = scale_out[row];
    const float c  = sx * 1.4426950408889634f;   // fold log2(e) into sx

    const int*  rowp = x_q   + (size_t)row * S;
    float*      outp = out_q + (size_t)row * S;

    float e[8][4];
    float s = 0.0f;

    #pragma unroll
    for (int ch = 0; ch < 8; ++ch) {
        const int jb = ch * 256;
        const int j0 = jb + lane * 4;
        if (jb + 255 <= i) {
            // fully valid chunk — wave-uniform, no per-lane masks
            vint4 q = __builtin_nontemporal_load(
                        reinterpret_cast<const vint4*>(rowp + j0));
            e[ch][0] = __builtin_amdgcn_exp2f((float)q.x * c);
            e[ch][1] = __builtin_amdgcn_exp2f((float)q.y * c);
            e[ch][2] = __builtin_amdgcn_exp2f((float)q.z * c);
            e[ch][3] = __builtin_amdgcn_exp2f((float)q.w * c);
            s += (e[ch][0] + e[ch][1]) + (e[ch][2] + e[ch][3]);
        } else if (jb <= i) {
            // boundary chunk — per-lane predication
            vint4 q = (vint4)(0);
            if (j0 <= i) q = __builtin_nontemporal_load(
                               reinterpret_cast<const vint4*>(rowp + j0));
            e[ch][0] = (j0 + 0 <= i) ? __builtin_amdgcn_exp2f((float)q.x * c) : 0.0f;
            e[ch][1] = (j0 + 1 <= i) ? __builtin_amdgcn_exp2f((float)q.y * c) : 0.0f;
            e[ch][2] = (j0 + 2 <= i) ? __builtin_amdgcn_exp2f((float)q.z * c) : 0.0f;
            e[ch][3] = (j0 + 3 <= i) ? __builtin_amdgcn_exp2f((float)q.w * c) : 0.0f;
            s += (e[ch][0] + e[ch][1]) + (e[ch][2] + e[ch][3]);
        } else {
            // fully masked chunk — wave-uniform, nothing issued
            e[ch][0] = 0.0f; e[ch][1] = 0.0f; e[ch][2] = 0.0f; e[ch][3] = 0.0f;
        }
    }

    // ---- wave sum: 6 shuffles, no LDS, no barrier ----
    #pragma unroll
    for (int off = 32; off > 0; off >>= 1)
        s += __shfl_xor(s, off, 64);

    // ---- quantize: clip(round(e / (s*so))); p >= 0 so only the high clamp ----
    const float scale = 1.0f / (s * so);

    #pragma unroll
    for (int ch = 0; ch < 8; ++ch) {
        const int j0 = ch * 256 + lane * 4;
        vfloat4 o;
        o.x = fminf(rintf(e[ch][0] * scale), 127.0f);
        o.y = fminf(rintf(e[ch][1] * scale), 127.0f);
        o.z = fminf(rintf(e[ch][2] * scale), 127.0f);
        o.w = fminf(rintf(e[ch][3] * scale), 127.0f);
        __builtin_nontemporal_store(o, reinterpret_cast<vfloat4*>(outp + j0));
    }

    // second tuple output: so = scale_out[:, :S]
    if (lane == 0) so_out[row] = so;
}

extern "C" void kernel_launch(void* const* d_in, const int* in_sizes, int n_in,
                              void* d_out, int out_size, void* d_ws, size_t ws_size,
                              hipStream_t stream) {
    const int*   x_q       = (const int*)d_in[0];
    const float* scale_x   = (const float*)d_in[1];
    const float* scale_out = (const float*)d_in[2];

    float* out    = (float*)d_out;
    float* so_out = out + OUTQ_ELEMS;   // second tuple output, concatenated flat

    dim3 grid(HS / 4);   // 8192 blocks, 4 rows (waves) each
    dim3 block(256);
    softmax_quant_wave_kernel<<<grid, block, 0, stream>>>(
        x_q, scale_x, scale_out, out, so_out);
}

// Round 5
// 76.255 us; speedup vs baseline: 1.0093x; 1.0093x over previous
//
#include <hip/hip_runtime.h>
#include <math.h>

// Problem constants (B=1, H=16, S=2048, MAX_SEQ_LEN=2048 == S)
constexpr int S = 2048;
constexpr int HS = 16 * S;             // number of rows = H*S
constexpr long long OUTQ_ELEMS = (long long)HS * S;  // 67,108,864

// Native clang vector types — required by __builtin_nontemporal_load/store.
typedef int   vint4   __attribute__((ext_vector_type(4)));
typedef float vfloat4 __attribute__((ext_vector_type(4)));

// One WAVE per row, 4 rows per 256-thread block — but unlike round 4, NO
// wave-uniform branches around the loads: all 8 chunk loads are issued
// back-to-back with per-lane exec-mask predication so they pipeline (8
// outstanding loads/thread). exp+mask runs in arrival order; reduction is
// 6 shfl_xor (no LDS, no barrier); stores reuse the e registers.
//
// Numerics: x = x_q*sx, x_q in [-64,63], sx in [0.005,0.02] => x in
// [-1.28,1.26]; exp in [0.28,3.53], row sum <= 7230 — softmax without
// max-subtraction is exact-safe in fp32 (absmax 0.0 measured, rounds 3/4).
__global__ __launch_bounds__(256) void softmax_quant_wave_kernel(
    const int*   __restrict__ x_q,       // (H, S, S) int32
    const float* __restrict__ scale_x,   // (H, 2048)
    const float* __restrict__ scale_out, // (H, 2048)
    float*       __restrict__ out_q,     // (H, S, S) as float32
    float*       __restrict__ so_out)    // (H, S)    as float32
{
    const int tid  = threadIdx.x;
    const int lane = tid & 63;
    const int wave = tid >> 6;
    const int row  = blockIdx.x * 4 + wave;   // h*S + i
    const int i    = row & (S - 1);

    const float sx = scale_x[row];
    const float so = scale_out[row];
    const float c  = sx * 1.4426950408889634f;   // fold log2(e) into sx

    const int*  rowp = x_q   + (size_t)row * S;
    float*      outp = out_q + (size_t)row * S;

    // ---- issue all 8 predicated loads back-to-back (no scalar branches) ----
    vint4 q[8];
    #pragma unroll
    for (int ch = 0; ch < 8; ++ch) {
        const int j0 = ch * 256 + lane * 4;
        q[ch] = (vint4)(0);
        if (j0 <= i)
            q[ch] = __builtin_nontemporal_load(
                      reinterpret_cast<const vint4*>(rowp + j0));
    }

    // ---- exp + causal mask, consumed in arrival order; running sum ----
    float e[8][4];
    float s = 0.0f;
    #pragma unroll
    for (int ch = 0; ch < 8; ++ch) {
        const int j0 = ch * 256 + lane * 4;
        e[ch][0] = (j0 + 0 <= i) ? __builtin_amdgcn_exp2f((float)q[ch].x * c) : 0.0f;
        e[ch][1] = (j0 + 1 <= i) ? __builtin_amdgcn_exp2f((float)q[ch].y * c) : 0.0f;
        e[ch][2] = (j0 + 2 <= i) ? __builtin_amdgcn_exp2f((float)q[ch].z * c) : 0.0f;
        e[ch][3] = (j0 + 3 <= i) ? __builtin_amdgcn_exp2f((float)q[ch].w * c) : 0.0f;
        s += (e[ch][0] + e[ch][1]) + (e[ch][2] + e[ch][3]);
    }

    // ---- wave sum: 6 shuffles, no LDS, no barrier ----
    #pragma unroll
    for (int off = 32; off > 0; off >>= 1)
        s += __shfl_xor(s, off, 64);

    // ---- quantize: clip(round(e/(s*so))); p >= 0 so only the high clamp ----
    const float scale = 1.0f / (s * so);

    #pragma unroll
    for (int ch = 0; ch < 8; ++ch) {
        const int j0 = ch * 256 + lane * 4;
        vfloat4 o;
        o.x = fminf(rintf(e[ch][0] * scale), 127.0f);
        o.y = fminf(rintf(e[ch][1] * scale), 127.0f);
        o.z = fminf(rintf(e[ch][2] * scale), 127.0f);
        o.w = fminf(rintf(e[ch][3] * scale), 127.0f);
        __builtin_nontemporal_store(o, reinterpret_cast<vfloat4*>(outp + j0));
    }

    // second tuple output: so = scale_out[:, :S]
    if (lane == 0) so_out[row] = so;
}

extern "C" void kernel_launch(void* const* d_in, const int* in_sizes, int n_in,
                              void* d_out, int out_size, void* d_ws, size_t ws_size,
                              hipStream_t stream) {
    const int*   x_q       = (const int*)d_in[0];
    const float* scale_x   = (const float*)d_in[1];
    const float* scale_out = (const float*)d_in[2];

    float* out    = (float*)d_out;
    float* so_out = out + OUTQ_ELEMS;   // second tuple output, concatenated flat

    dim3 grid(HS / 4);   // 8192 blocks, 4 rows (one wave each)
    dim3 block(256);
    softmax_quant_wave_kernel<<<grid, block, 0, stream>>>(
        x_q, scale_x, scale_out, out, so_out);
}

// Round 6
// 73.443 us; speedup vs baseline: 1.0479x; 1.0383x over previous
//
#include <hip/hip_runtime.h>
#include <math.h>

// Problem constants (B=1, H=16, S=2048, MAX_SEQ_LEN=2048 == S)
constexpr int S = 2048;
constexpr int HS = 16 * S;             // number of rows = H*S
constexpr long long OUTQ_ELEMS = (long long)HS * S;  // 67,108,864

// Native clang vector types — required by __builtin_nontemporal_load/store.
typedef int   vint4   __attribute__((ext_vector_type(4)));
typedef float vfloat4 __attribute__((ext_vector_type(4)));

// TWO adjacent rows per 256-thread block (rows 2b, 2b+1 — same causal length
// ±1, so balanced). Per thread: 4 predicated int4 loads issued back-to-back
// (deep MLP), exp for both rows, interleaved dual shfl reduction (two
// independent 6-step chains overlap), ONE barrier for both rows, 4 stores.
// This halves the per-row barrier/LDS cost vs the round-3 best (70.2 us)
// while keeping ~50 VGPRs -> 8 waves/SIMD.
//
// Numerics: x = x_q*sx, x_q in [-64,63], sx in [0.005,0.02] => x in
// [-1.28,1.26]; exp in [0.28,3.53], row sum <= 7230 — softmax without
// max-subtraction is exact-safe in fp32 (absmax 0.0, rounds 3-5). p >= 0 so
// the -128 clamp is dead.
__global__ __launch_bounds__(256) void softmax_quant_2row_kernel(
    const int*   __restrict__ x_q,       // (H, S, S) int32
    const float* __restrict__ scale_x,   // (H, 2048)
    const float* __restrict__ scale_out, // (H, 2048)
    float*       __restrict__ out_q,     // (H, S, S) as float32
    float*       __restrict__ so_out)    // (H, S)    as float32
{
    const int tid  = threadIdx.x;
    const int rowA = blockIdx.x * 2;      // global row = h*S + i, even
    const int rowB = rowA + 1;            // same head (S even)
    const int iA   = rowA & (S - 1);
    const int iB   = iA + 1;

    const float sxA = scale_x[rowA];
    const float sxB = scale_x[rowB];
    const float soA = scale_out[rowA];
    const float soB = scale_out[rowB];
    const float cA  = sxA * 1.4426950408889634f;
    const float cB  = sxB * 1.4426950408889634f;

    const int* rowpA = x_q + (size_t)rowA * S;
    const int* rowpB = x_q + (size_t)rowB * S;

    const int j0 = tid * 4;
    const int j1 = j0 + (S / 2);

    // ---- 4 predicated loads, back-to-back (no scalar branches) ----
    vint4 qa0 = (vint4)(0), qa1 = (vint4)(0);
    vint4 qb0 = (vint4)(0), qb1 = (vint4)(0);
    if (j0 <= iA) qa0 = __builtin_nontemporal_load(
                          reinterpret_cast<const vint4*>(rowpA + j0));
    if (j1 <= iA) qa1 = __builtin_nontemporal_load(
                          reinterpret_cast<const vint4*>(rowpA + j1));
    if (j0 <= iB) qb0 = __builtin_nontemporal_load(
                          reinterpret_cast<const vint4*>(rowpB + j0));
    if (j1 <= iB) qb1 = __builtin_nontemporal_load(
                          reinterpret_cast<const vint4*>(rowpB + j1));

    // ---- exp + causal mask, both rows ----
    float ea[8], eb[8];
    ea[0] = (j0 + 0 <= iA) ? __builtin_amdgcn_exp2f((float)qa0.x * cA) : 0.0f;
    ea[1] = (j0 + 1 <= iA) ? __builtin_amdgcn_exp2f((float)qa0.y * cA) : 0.0f;
    ea[2] = (j0 + 2 <= iA) ? __builtin_amdgcn_exp2f((float)qa0.z * cA) : 0.0f;
    ea[3] = (j0 + 3 <= iA) ? __builtin_amdgcn_exp2f((float)qa0.w * cA) : 0.0f;
    ea[4] = (j1 + 0 <= iA) ? __builtin_amdgcn_exp2f((float)qa1.x * cA) : 0.0f;
    ea[5] = (j1 + 1 <= iA) ? __builtin_amdgcn_exp2f((float)qa1.y * cA) : 0.0f;
    ea[6] = (j1 + 2 <= iA) ? __builtin_amdgcn_exp2f((float)qa1.z * cA) : 0.0f;
    ea[7] = (j1 + 3 <= iA) ? __builtin_amdgcn_exp2f((float)qa1.w * cA) : 0.0f;
    eb[0] = (j0 + 0 <= iB) ? __builtin_amdgcn_exp2f((float)qb0.x * cB) : 0.0f;
    eb[1] = (j0 + 1 <= iB) ? __builtin_amdgcn_exp2f((float)qb0.y * cB) : 0.0f;
    eb[2] = (j0 + 2 <= iB) ? __builtin_amdgcn_exp2f((float)qb0.z * cB) : 0.0f;
    eb[3] = (j0 + 3 <= iB) ? __builtin_amdgcn_exp2f((float)qb0.w * cB) : 0.0f;
    eb[4] = (j1 + 0 <= iB) ? __builtin_amdgcn_exp2f((float)qb1.x * cB) : 0.0f;
    eb[5] = (j1 + 1 <= iB) ? __builtin_amdgcn_exp2f((float)qb1.y * cB) : 0.0f;
    eb[6] = (j1 + 2 <= iB) ? __builtin_amdgcn_exp2f((float)qb1.z * cB) : 0.0f;
    eb[7] = (j1 + 3 <= iB) ? __builtin_amdgcn_exp2f((float)qb1.w * cB) : 0.0f;

    float sa = ((ea[0] + ea[1]) + (ea[2] + ea[3])) + ((ea[4] + ea[5]) + (ea[6] + ea[7]));
    float sb = ((eb[0] + eb[1]) + (eb[2] + eb[3])) + ((eb[4] + eb[5]) + (eb[6] + eb[7]));

    // ---- dual interleaved wave reduction (chains overlap) ----
    #pragma unroll
    for (int off = 32; off > 0; off >>= 1) {
        sa += __shfl_xor(sa, off, 64);
        sb += __shfl_xor(sb, off, 64);
    }

    // ---- single cross-wave step for BOTH rows ----
    __shared__ float red[4][2];
    const int wave = tid >> 6;
    if ((tid & 63) == 0) { red[wave][0] = sa; red[wave][1] = sb; }
    __syncthreads();
    sa = (red[0][0] + red[1][0]) + (red[2][0] + red[3][0]);
    sb = (red[0][1] + red[1][1]) + (red[2][1] + red[3][1]);

    // ---- quantize: p >= 0 so only the high clamp ----
    const float scaleA = 1.0f / (sa * soA);
    const float scaleB = 1.0f / (sb * soB);

    float* outpA = out_q + (size_t)rowA * S;
    float* outpB = out_q + (size_t)rowB * S;

    vfloat4 o;
    o.x = fminf(rintf(ea[0] * scaleA), 127.0f);
    o.y = fminf(rintf(ea[1] * scaleA), 127.0f);
    o.z = fminf(rintf(ea[2] * scaleA), 127.0f);
    o.w = fminf(rintf(ea[3] * scaleA), 127.0f);
    __builtin_nontemporal_store(o, reinterpret_cast<vfloat4*>(outpA + j0));
    o.x = fminf(rintf(ea[4] * scaleA), 127.0f);
    o.y = fminf(rintf(ea[5] * scaleA), 127.0f);
    o.z = fminf(rintf(ea[6] * scaleA), 127.0f);
    o.w = fminf(rintf(ea[7] * scaleA), 127.0f);
    __builtin_nontemporal_store(o, reinterpret_cast<vfloat4*>(outpA + j1));
    o.x = fminf(rintf(eb[0] * scaleB), 127.0f);
    o.y = fminf(rintf(eb[1] * scaleB), 127.0f);
    o.z = fminf(rintf(eb[2] * scaleB), 127.0f);
    o.w = fminf(rintf(eb[3] * scaleB), 127.0f);
    __builtin_nontemporal_store(o, reinterpret_cast<vfloat4*>(outpB + j0));
    o.x = fminf(rintf(eb[4] * scaleB), 127.0f);
    o.y = fminf(rintf(eb[5] * scaleB), 127.0f);
    o.z = fminf(rintf(eb[6] * scaleB), 127.0f);
    o.w = fminf(rintf(eb[7] * scaleB), 127.0f);
    __builtin_nontemporal_store(o, reinterpret_cast<vfloat4*>(outpB + j1));

    // second tuple output: so = scale_out[:, :S]
    if (tid == 0) { so_out[rowA] = soA; so_out[rowB] = soB; }
}

extern "C" void kernel_launch(void* const* d_in, const int* in_sizes, int n_in,
                              void* d_out, int out_size, void* d_ws, size_t ws_size,
                              hipStream_t stream) {
    const int*   x_q       = (const int*)d_in[0];
    const float* scale_x   = (const float*)d_in[1];
    const float* scale_out = (const float*)d_in[2];

    float* out    = (float*)d_out;
    float* so_out = out + OUTQ_ELEMS;   // second tuple output, concatenated flat

    dim3 grid(HS / 2);   // 16384 blocks, 2 adjacent rows each
    dim3 block(256);
    softmax_quant_2row_kernel<<<grid, block, 0, stream>>>(
        x_q, scale_x, scale_out, out, so_out);
}

// Round 7
// 69.336 us; speedup vs baseline: 1.1100x; 1.0592x over previous
//
#include <hip/hip_runtime.h>
#include <math.h>

// Problem constants (B=1, H=16, S=2048, MAX_SEQ_LEN=2048 == S)
constexpr int S = 2048;
constexpr int HS = 16 * S;             // number of rows = H*S
constexpr long long OUTQ_ELEMS = (long long)HS * S;  // 67,108,864

// Native clang vector types — required by __builtin_nontemporal_load/store.
typedef int   vint4   __attribute__((ext_vector_type(4)));
typedef float vfloat4 __attribute__((ext_vector_type(4)));

// PROVEN-BEST structure (round 3, 70.2 us): one 256-thread block per row,
// 8 elements/thread as two predicated int4 chunks, single block-sum
// reduction, nontemporal streaming. Rounds 4-6 (wave-per-row, 2-row
// blocks) all regressed: extra live registers across the barrier cost more
// than the saved sync — at 8 waves/SIMD the barrier is already TLP-hidden.
// Deltas vs round 3 (provably free): dead -128 clamp removed (p >= 0);
// so_out store hoisted above the barrier.
//
// Numerics: x = x_q*sx, x_q in [-64,63], sx in [0.005,0.02] => x in
// [-1.28,1.26]; exp in [0.28,3.53], row sum <= 7230 — softmax without
// max-subtraction is exact-safe in fp32 (absmax 0.0, rounds 3-6).
__global__ __launch_bounds__(256) void softmax_quant_row_kernel(
    const int*   __restrict__ x_q,       // (H, S, S) int32
    const float* __restrict__ scale_x,   // (H, 2048)
    const float* __restrict__ scale_out, // (H, 2048)
    float*       __restrict__ out_q,     // (H, S, S) as float32
    float*       __restrict__ so_out)    // (H, S)    as float32
{
    const int row = blockIdx.x;          // h*S + i
    const int i   = row & (S - 1);       // row index within the S x S matrix
    const int tid = threadIdx.x;

    const float sx = scale_x[row];
    const float so = scale_out[row];

    const int*  rowp = x_q   + (size_t)row * S;
    float*      outp = out_q + (size_t)row * S;

    const int j0 = tid * 4;
    const int j1 = j0 + (S / 2);

    // Predicated coalesced nontemporal loads: skip chunks past the causal bound.
    vint4 q0 = (vint4)(0);
    vint4 q1 = (vint4)(0);
    if (j0 <= i) q0 = __builtin_nontemporal_load(
                        reinterpret_cast<const vint4*>(rowp + j0));
    if (j1 <= i) q1 = __builtin_nontemporal_load(
                        reinterpret_cast<const vint4*>(rowp + j1));

    // second tuple output: so = scale_out[:, :S] — independent of the sum
    if (tid == 0) so_out[row] = so;

    // exp(q * sx) = exp2(q * (sx*log2e)) — fold the base-2 conversion into sx.
    const float c = sx * 1.4426950408889634f;

    float e[8];
    e[0] = (j0 + 0 <= i) ? __builtin_amdgcn_exp2f((float)q0.x * c) : 0.0f;
    e[1] = (j0 + 1 <= i) ? __builtin_amdgcn_exp2f((float)q0.y * c) : 0.0f;
    e[2] = (j0 + 2 <= i) ? __builtin_amdgcn_exp2f((float)q0.z * c) : 0.0f;
    e[3] = (j0 + 3 <= i) ? __builtin_amdgcn_exp2f((float)q0.w * c) : 0.0f;
    e[4] = (j1 + 0 <= i) ? __builtin_amdgcn_exp2f((float)q1.x * c) : 0.0f;
    e[5] = (j1 + 1 <= i) ? __builtin_amdgcn_exp2f((float)q1.y * c) : 0.0f;
    e[6] = (j1 + 2 <= i) ? __builtin_amdgcn_exp2f((float)q1.z * c) : 0.0f;
    e[7] = (j1 + 3 <= i) ? __builtin_amdgcn_exp2f((float)q1.w * c) : 0.0f;
    float s = ((e[0] + e[1]) + (e[2] + e[3])) + ((e[4] + e[5]) + (e[6] + e[7]));

    // ---- block sum (single reduction, single barrier) ----
    #pragma unroll
    for (int off = 32; off > 0; off >>= 1)
        s += __shfl_xor(s, off, 64);

    __shared__ float redsum[4];
    const int wave = tid >> 6;
    if ((tid & 63) == 0) redsum[wave] = s;
    __syncthreads();
    s = (redsum[0] + redsum[1]) + (redsum[2] + redsum[3]);

    // ---- quantize: clip(round(p / so)); p >= 0 so only the high clamp ----
    const float scale = 1.0f / (s * so);

    vfloat4 o0, o1;
    o0.x = fminf(rintf(e[0] * scale), 127.0f);
    o0.y = fminf(rintf(e[1] * scale), 127.0f);
    o0.z = fminf(rintf(e[2] * scale), 127.0f);
    o0.w = fminf(rintf(e[3] * scale), 127.0f);
    o1.x = fminf(rintf(e[4] * scale), 127.0f);
    o1.y = fminf(rintf(e[5] * scale), 127.0f);
    o1.z = fminf(rintf(e[6] * scale), 127.0f);
    o1.w = fminf(rintf(e[7] * scale), 127.0f);

    __builtin_nontemporal_store(o0, reinterpret_cast<vfloat4*>(outp + j0));
    __builtin_nontemporal_store(o1, reinterpret_cast<vfloat4*>(outp + j1));
}

extern "C" void kernel_launch(void* const* d_in, const int* in_sizes, int n_in,
                              void* d_out, int out_size, void* d_ws, size_t ws_size,
                              hipStream_t stream) {
    const int*   x_q       = (const int*)d_in[0];
    const float* scale_x   = (const float*)d_in[1];
    const float* scale_out = (const float*)d_in[2];

    float* out    = (float*)d_out;
    float* so_out = out + OUTQ_ELEMS;   // second tuple output, concatenated flat

    dim3 grid(HS);   // 32768 rows
    dim3 block(256);
    softmax_quant_row_kernel<<<grid, block, 0, stream>>>(
        x_q, scale_x, scale_out, out, so_out);
}